// Round 3
// baseline (647.115 us; speedup 1.0000x reference)
//
#include <hip/hip_runtime.h>
#include <hip/hip_bf16.h>
#include <math.h>

// Problem constants
#define Bd 32
#define Sd 32
#define Ld 64
#define Ed 128
#define Hd 128
#define MW 65536   // B*S*L tokens
#define MS 1024    // B*S sentences

// ws layout (float offsets)
#define OFF_WIHT_S   0          // [k=256][g=768] sentence input-proj weights (fp32)
#define OFF_WFW_W    196608     // 131072 u16: word attn Ww B-frags hi/lo
#define OFF_WFW_S    262144     // 131072 u16: sent attn Ws B-frags hi/lo
#define OFF_W6       327680     // 6 sets x float4[k4=32][g=384] (sets 4,5 used: sentence GRU)
#define OFF_BIH_W    622592     // (unused, kept)
#define OFF_BIH_S    623360
#define OFF_BHH_W    624128     // (unused, kept)
#define OFF_BHH_S    624896
#define OFF_WFX      625664     // 196608 u16: word xp w_ih B-frags [dir][half][nt24][q4][l][e]
#define OFF_HW       723968     // 1024 sents x [t64][hilo2][k256] u16 = 33.5M u16
#define OFF_SENTS    17763328   // 1024 x 256
#define OFF_XP_S     18025472   // 1024 x 768
#define OFF_HS       18811904   // 1024 x 256
#define OFF_DOC      19078144   // 32 x 256
#define OFF_WFHH     19086336   // 196608 u16: W_hh MFMA B-frags hi/lo
#define WS_FLOATS    19184640   // 76.7 MB

typedef __attribute__((ext_vector_type(8))) short sh8;
typedef __attribute__((ext_vector_type(4))) float f32x4;
typedef unsigned short u16;
typedef unsigned int u32;

#define XPLD 385   // xp_lds stride (mod 32 = 1 -> banks spread)
#define HPLD 520   // h_pk per-q stride in u16 (q-pad spreads banks)

__device__ __forceinline__ float sigmoidf_(float x) {
    return __fdividef(1.0f, 1.0f + __expf(-x));
}
__device__ __forceinline__ float tanhf_(float x) {
    float t = __expf(-2.0f * fabsf(x));
    float r = __fdividef(1.0f - t, 1.0f + t);
    return copysignf(r, x);
}
__device__ __forceinline__ u16 bf16_hi(float f) {
    u32 x = __float_as_uint(f);
    return (u16)((x + 0x7fffu + ((x >> 16) & 1u)) >> 16);
}
__device__ __forceinline__ float bf16_f(u16 u) { return __uint_as_float(((u32)u) << 16); }
__device__ __forceinline__ void bf16_split(float f, u16& hi, u16& lo) {
    hi = bf16_hi(f);
    lo = bf16_hi(f - bf16_f(hi));
}

// ---------------- weight prep ----------------
__global__ void prep(const float* __restrict__ s_ih_f, const float* __restrict__ s_ih_b,
                     const float* __restrict__ w_ih_f, const float* __restrict__ w_ih_b,
                     const float* __restrict__ w_hh_f, const float* __restrict__ w_hh_b,
                     const float* __restrict__ s_hh_f, const float* __restrict__ s_hh_b,
                     const float* __restrict__ b_ih_f, const float* __restrict__ b_ih_b,
                     const float* __restrict__ sb_ih_f, const float* __restrict__ sb_ih_b,
                     const float* __restrict__ b_hh_f, const float* __restrict__ b_hh_b,
                     const float* __restrict__ sb_hh_f, const float* __restrict__ sb_hh_b,
                     float* __restrict__ ws)
{
    int i = blockIdx.x * 256 + threadIdx.x;
    if (i < 196608) {  // WIHT_S [k=256][768]
        int k = i / 768, g = i % 768;
        ws[OFF_WIHT_S + i] = (g < 384) ? s_ih_f[g*256 + k] : s_ih_b[(g-384)*256 + k];
        return;
    }
    i -= 196608;
    if (i < 131072) return;   // frag buffers written by prep3
    i -= 131072;
    if (i < 294912) {  // W6 (sets 4,5 used by sentence GRU)
        int set = i / 49152, rem = i % 49152;
        int k4 = rem / 1536, r2 = rem % 1536, g = r2 >> 2, sub = r2 & 3;
        const float* w = (set==0) ? w_ih_f : (set==1) ? w_ih_b : (set==2) ? w_hh_f
                       : (set==3) ? w_hh_b : (set==4) ? s_hh_f : s_hh_b;
        ws[OFF_W6 + i] = w[g*128 + k4*4 + sub];
        return;
    }
    i -= 294912;
    if (i < 768) { ws[OFF_BIH_W + i] = (i<384) ? b_ih_f[i] : b_ih_b[i-384]; return; }
    i -= 768;
    if (i < 768) { ws[OFF_BIH_S + i] = (i<384) ? sb_ih_f[i] : sb_ih_b[i-384]; return; }
    i -= 768;
    if (i < 768) { ws[OFF_BHH_W + i] = (i<384) ? b_hh_f[i] : b_hh_b[i-384]; return; }
    i -= 768;
    if (i < 768) { ws[OFF_BHH_S + i] = (i<384) ? sb_hh_f[i] : sb_hh_b[i-384]; return; }
}

// ---------------- prep2: W_hh into MFMA B-frag order, bf16 hi/lo ----------------
// layout: [dir2][half2][nt24][q4][lane64][elem8] ushort
__global__ void prep2(const float* __restrict__ w_hh_f, const float* __restrict__ w_hh_b,
                      u16* __restrict__ WFo)
{
    int i = blockIdx.x * 256 + threadIdx.x;   // < 196608
    int within = i % 49152;
    int combo  = i / 49152;      // dir*2 + half
    int half = combo & 1, dir = combo >> 1;
    int nt  = within / 2048;
    int r2  = within % 2048;
    int q   = r2 >> 9;
    int r3  = r2 & 511;
    int l   = r3 >> 3, e = r3 & 7;
    int n = nt*16 + (l & 15);
    int k = q*32 + ((l >> 4) << 3) + e;
    const float* src = dir ? w_hh_b : w_hh_f;
    float v = src[n*128 + k];
    u16 hi = bf16_hi(v);
    WFo[i] = half ? bf16_hi(v - bf16_f(hi)) : hi;
}

// ---------------- prep3: attn (Ww,Ws) and xp (w_ih) weights into B-frag hi/lo ---------
// WFW_*: [half2][nt16][q8][l64][e8]; WFX: [dir2][half2][nt24][q4][l64][e8]
__global__ void prep3(const float* __restrict__ Ww, const float* __restrict__ Ws,
                      const float* __restrict__ w_ih_f, const float* __restrict__ w_ih_b,
                      u16* __restrict__ WFW_W, u16* __restrict__ WFW_S,
                      u16* __restrict__ WFX)
{
    int i = blockIdx.x * 256 + threadIdx.x;   // < 458752
    if (i < 262144) {
        int which = i / 131072;       // 0=Ww, 1=Ws
        int w = i % 131072;
        int half = w / 65536;
        int r = w % 65536;
        int nt = r / 4096;
        int r2 = r % 4096;
        int q = r2 / 512;
        int l = (r2 % 512) >> 3, e = r2 & 7;
        int n = nt*16 + (l & 15);
        int k = q*32 + ((l >> 4) << 3) + e;
        const float* src = which ? Ws : Ww;
        float v = src[n*256 + k];
        u16 hi = bf16_hi(v);
        u16 o = half ? bf16_hi(v - bf16_f(hi)) : hi;
        (which ? WFW_S : WFW_W)[w] = o;
        return;
    }
    i -= 262144;
    if (i < 196608) {
        int w = i % 98304;
        int dir = i / 98304;
        int half = w / 49152;
        int r = w % 49152;
        int nt = r / 2048;
        int r2 = r % 2048;
        int q = r2 / 512;
        int l = (r2 % 512) >> 3, e = r2 & 7;
        int n = nt*16 + (l & 15);
        int k = q*32 + ((l >> 4) << 3) + e;
        const float* src = dir ? w_ih_b : w_ih_f;
        float v = src[n*128 + k];
        u16 hi = bf16_hi(v);
        WFX[i] = half ? bf16_hi(v - bf16_f(hi)) : hi;
        return;
    }
}

// ---- staging helper: one (token, k-pair) item of embedding gather -> a_pk ----
__device__ __forceinline__ void stage_emb(int idx, int c, int dir,
                                          const float* __restrict__ emb,
                                          const int (*ids_s)[64],
                                          u16* __restrict__ a_pk)
{
    int cc = idx & 3, rm = (idx >> 2) & 7, subk = (idx >> 5) & 3;
    int q = (idx >> 7) & 3, mfs = idx >> 9;
    int ts = c*8 + rm;
    int t = dir ? 63 - ts : ts;
    int kk = q*32 + subk*8 + cc*2;
    int id = ids_s[mfs][t];
    float2 v = make_float2(0.f, 0.f);
    if (id != 0) v = *(const float2*)&emb[(long)id*128 + kk];
    u16 h0,l0,h1,l1; bf16_split(v.x,h0,l0); bf16_split(v.y,h1,l1);
    int lh = subk*16 + rm;
    *(u32*)&a_pk[(mfs*4 + q)*512 + lh*8 + cc*2]       = (u32)h0 | ((u32)h1 << 16);
    *(u32*)&a_pk[(mfs*4 + q)*512 + (lh+8)*8 + cc*2]   = (u32)l0 | ((u32)l1 << 16);
}

// ---------------- fused word pipeline: gather + xp-GEMM (LDS) + recurrence ----------
// ROUND-17: round-16 structure, register-budget fix v2.
//  * __launch_bounds__(768,3) was a NO-OP (VGPR_Count 84 both with and without it):
//    for a 12-wave workgroup the default waves-per-EU minimum is already 3, so the
//    hint restated the default and the allocator kept its ~84-reg (6 waves/EU)
//    budget, spilling the 96-VGPR W_hh frag set to scratch (347MB FETCH / 271MB
//    WRITE, MfmaUtil 8.8%).
//  * Fix: explicit amdgpu_waves_per_eu(3,3) — pinning min AND max occupancy. Budget
//    becomes 512/3 -> 168 regs, which holds the step-loop live set (~145).
//    Occupancy is unchanged (LDS already caps at 1 block = 12 waves/CU).
//  * tt loop forced to no-unroll (#pragma unroll 1): serial recurrence gains nothing
//    from unrolling; containing it shrinks cross-iteration live ranges.
__global__ __launch_bounds__(768) __attribute__((amdgpu_waves_per_eu(3, 3)))
void gru_word_full(const int* __restrict__ X, const float* __restrict__ emb,
                   const u16* __restrict__ WFX, const u16* __restrict__ WFHH,
                   const float* __restrict__ b_ih_f, const float* __restrict__ b_ih_b,
                   const float* __restrict__ b_hh_f, const float* __restrict__ b_hh_b,
                   u16* __restrict__ houtp)
{
    const int bx = blockIdx.x;
    const int dir = bx >> 7;
    const int blk = bx & 127;
    const int seq0 = blk * 8;
    const int tid = threadIdx.x;
    const int lane = tid & 63;
    const int wid = tid >> 6;            // 0..11; 0-7 compute, 8-11 stage

    __shared__ float xp_lds[64 * XPLD];      // 98560 B (rows = s*8 + tt)
    __shared__ u16 a_pk[8 * 4 * 512];        // 32768 B embedding frags (per chunk)
    __shared__ u16 h_pk[4 * HPLD];           // 4160 B (hi rows 0-7, lo rows 8-15)
    __shared__ int ids_s[8][64];             // 2048 B

    const float* bih = dir ? b_ih_b : b_ih_f;
    const float* bhh = dir ? b_hh_b : b_hh_f;

    const u16* WXbase = WFX + (long)dir * 98304;
    const u16* WHbase = WFHH + (long)dir * 98304;
    const int nt0 = wid*2, nt1 = wid*2 + 1;
    const int c0 = nt0*16 + (lane & 15);
    const int c1 = nt1*16 + (lane & 15);

    // compute-wave gate geometry (valid for wid<8):
    // lane -> (col j, 2 seqs). After shfl_xor(32), acc row r holds the full hi+lo gate
    // sum: lanes 0-15 -> seqs 0,1 (r=0,1); 16-31 -> seqs 4,5 (r=0,1);
    //      lanes 32-47 -> seqs 2,3 (r=2,3); 48-63 -> seqs 6,7 (r=2,3).
    const int col16 = lane & 15;
    const int j  = wid*16 + col16;
    const int half = lane >> 5;
    const int lq   = (lane >> 4) & 1;
    const int sb   = lq*4 + half*2;      // first of this lane's 2 seqs
    const int r0   = half*2;             // acc row index for first seq
    const int qj = j >> 5, subkj = (j >> 3) & 3, ej = j & 7;
    float bhr = 0.f, bhz = 0.f, bhn = 0.f;
    if (wid < 8) { bhr = bhh[j]; bhz = bhh[128 + j]; bhn = bhh[256 + j]; }

    for (int i = tid; i < 512; i += 768)
        ids_s[i >> 6][i & 63] = X[(long)(seq0 + (i >> 6))*64 + (i & 63)];
    for (int i = tid; i < 4*HPLD; i += 768) h_pk[i] = 0;
    __syncthreads();

    // prologue: stage chunk 0 with all 768 threads
    for (int idx = tid; idx < 4096; idx += 768)
        stage_emb(idx, 0, dir, emb, ids_s, a_pk);
    __syncthreads();

    float hprev0 = 0.f, hprev1 = 0.f;
    for (int c = 0; c < 8; ++c) {
        asm volatile("" ::: "memory");   // no cross-chunk hoisting of weight loads
        // ---- load W_ih frags (this chunk only) ----
        sh8 xh0[4], xl0[4], xh1[4], xl1[4];
#pragma unroll
        for (int q = 0; q < 4; ++q) {
            xh0[q] = *(const sh8*)(WXbase + (nt0*4 + q)*512 + lane*8);
            xl0[q] = *(const sh8*)(WXbase + 49152 + (nt0*4 + q)*512 + lane*8);
            xh1[q] = *(const sh8*)(WXbase + (nt1*4 + q)*512 + lane*8);
            xl1[q] = *(const sh8*)(WXbase + 49152 + (nt1*4 + q)*512 + lane*8);
        }
        const float bv0 = bih[c0], bv1 = bih[c1];
        // ---- xp MFMA: 8 m-frags -> xp_lds (+bias), half-dedup epilogue (all 12 waves) ----
#pragma unroll
        for (int mf = 0; mf < 8; ++mf) {
            f32x4 A0 = (f32x4){0.f,0.f,0.f,0.f};
            f32x4 A1 = (f32x4){0.f,0.f,0.f,0.f};
#pragma unroll
            for (int q = 0; q < 4; ++q) {
                sh8 a = *(const sh8*)&a_pk[(mf*4 + q)*512 + lane*8];
                A0 = __builtin_amdgcn_mfma_f32_16x16x32_bf16(a, xh0[q], A0, 0,0,0);
                A0 = __builtin_amdgcn_mfma_f32_16x16x32_bf16(a, xl0[q], A0, 0,0,0);
                A1 = __builtin_amdgcn_mfma_f32_16x16x32_bf16(a, xh1[q], A1, 0,0,0);
                A1 = __builtin_amdgcn_mfma_f32_16x16x32_bf16(a, xl1[q], A1, 0,0,0);
            }
            float g0[4], g1[4];
#pragma unroll
            for (int r = 0; r < 4; ++r) {
                g0[r] = A0[r] + __shfl_xor(A0[r], 32);
                g1[r] = A1[r] + __shfl_xor(A1[r], 32);
            }
            if ((lane >= 32) == (mf & 1)) {
                int row = mf*8 + ((lane >> 4) & 1)*4;
#pragma unroll
                for (int r = 0; r < 4; ++r) {
                    xp_lds[(row+r)*XPLD + c0] = g0[r] + bv0;
                    xp_lds[(row+r)*XPLD + c1] = g1[r] + bv1;
                }
            }
        }
        __syncthreads();   // xp ready; a_pk free for chunk c+1 staging
        asm volatile("" ::: "memory");
        // ---- compute waves: load W_hh frags for their 3 gate tiles ----
        sh8 wrh[4], wrl[4], wzh[4], wzl[4], wnh[4], wnl[4];
        if (wid < 8) {
#pragma unroll
            for (int q = 0; q < 4; ++q) {
                wrh[q] = *(const sh8*)(WHbase + ((wid     )*4 + q)*512 + lane*8);
                wrl[q] = *(const sh8*)(WHbase + 49152 + ((wid     )*4 + q)*512 + lane*8);
                wzh[q] = *(const sh8*)(WHbase + ((wid +  8)*4 + q)*512 + lane*8);
                wzl[q] = *(const sh8*)(WHbase + 49152 + ((wid +  8)*4 + q)*512 + lane*8);
                wnh[q] = *(const sh8*)(WHbase + ((wid + 16)*4 + q)*512 + lane*8);
                wnl[q] = *(const sh8*)(WHbase + 49152 + ((wid + 16)*4 + q)*512 + lane*8);
            }
        }
        // ---- 8 recurrence steps (compute waves) || chunk c+1 staging (stage waves) ----
#pragma unroll 1
        for (int tt = 0; tt < 8; ++tt) {
            if (wid < 8) {
                const int ts = c*8 + tt;
                const int t = dir ? 63 - ts : ts;
                sh8 hp[4];
#pragma unroll
                for (int q = 0; q < 4; ++q) hp[q] = *(const sh8*)&h_pk[q*HPLD + lane*8];
                f32x4 aR = (f32x4){0.f,0.f,0.f,0.f};
                f32x4 aZ = (f32x4){0.f,0.f,0.f,0.f};
                f32x4 aN = (f32x4){0.f,0.f,0.f,0.f};
#pragma unroll
                for (int q = 0; q < 4; ++q) {
                    aR = __builtin_amdgcn_mfma_f32_16x16x32_bf16(hp[q], wrh[q], aR, 0,0,0);
                    aR = __builtin_amdgcn_mfma_f32_16x16x32_bf16(hp[q], wrl[q], aR, 0,0,0);
                    aZ = __builtin_amdgcn_mfma_f32_16x16x32_bf16(hp[q], wzh[q], aZ, 0,0,0);
                    aZ = __builtin_amdgcn_mfma_f32_16x16x32_bf16(hp[q], wzl[q], aZ, 0,0,0);
                    aN = __builtin_amdgcn_mfma_f32_16x16x32_bf16(hp[q], wnh[q], aN, 0,0,0);
                    aN = __builtin_amdgcn_mfma_f32_16x16x32_bf16(hp[q], wnl[q], aN, 0,0,0);
                }
                float gR[4], gZ[4], gN[4];
#pragma unroll
                for (int r = 0; r < 4; ++r) {
                    gR[r] = aR[r] + __shfl_xor(aR[r], 32);
                    gZ[r] = aZ[r] + __shfl_xor(aZ[r], 32);
                    gN[r] = aN[r] + __shfl_xor(aN[r], 32);
                }
#pragma unroll
                for (int i = 0; i < 2; ++i) {
                    const int s = sb + i;
                    const int r = r0 + i;
                    float grt = gR[r] + bhr;
                    float gzt = gZ[r] + bhz;
                    float gnt = gN[r] + bhn;
                    const float* xrow = &xp_lds[(s*8 + tt)*XPLD];
                    float rg = sigmoidf_(xrow[j] + grt);
                    float zg = sigmoidf_(xrow[128 + j] + gzt);
                    float nv = tanhf_(xrow[256 + j] + rg * gnt);
                    float hold = i ? hprev1 : hprev0;
                    float hnew = (1.f - zg) * nv + zg * hold;
                    if (i) hprev1 = hnew; else hprev0 = hnew;
                    u16 hh, hl; bf16_split(hnew, hh, hl);
                    u16 ohh = (u16)__shfl_xor((int)hh, 1);
                    u16 ohl = (u16)__shfl_xor((int)hl, 1);
                    const long tbase = ((long)(seq0 + s)*64 + t)*512 + dir*128;
                    // paired u32 writes to BOTH h_pk (LDS) and hout (global), same word
                    if ((j & 1) == 0) {
                        u32 w = (u32)hh | ((u32)ohh << 16);
                        *(u32*)&h_pk[qj*HPLD + (subkj*16 + s)*8 + ej] = w;
                        *(u32*)&houtp[tbase + j] = w;
                    } else {
                        u32 w = (u32)ohl | ((u32)hl << 16);
                        *(u32*)&h_pk[qj*HPLD + (subkj*16 + s + 8)*8 + (ej - 1)] = w;
                        *(u32*)&houtp[tbase + 256 + (j - 1)] = w;
                    }
                }
            } else if (c < 7) {
                // stage waves: 2 items per step slice -> full 4096 over 8 steps
                const int st = tid - 512;                 // 0..255
                stage_emb(tt*512 + st,        c + 1, dir, emb, ids_s, a_pk);
                stage_emb(tt*512 + 256 + st,  c + 1, dir, emb, ids_s, a_pk);
            }
            __syncthreads();
        }
    }
}

// ---------------- fused attention: score MFMA + tanh/ctx + softmax + pool ----------
// PACKED=true: A = hout u16 [sent][t][hilo][k256]; staged via decode-permute copy.
// PACKED=false: A is fp32 [M][256], staged with bf16 split (sentence level).
template<int T, bool PACKED>
__global__ __launch_bounds__(1024)
void attn_fused(const float* __restrict__ A, const u16* __restrict__ WF,
                const float* __restrict__ bias, const float* __restrict__ ctx,
                float* __restrict__ outp)
{
    __shared__ u16 a_pk[8][8][512];    // 64 KB
    __shared__ float pscore[8][8][17];
    __shared__ float aw[64];
    __shared__ float red[4][256];
    const int tid = threadIdx.x;
    const int lane = tid & 63;
    const int wid = tid >> 6;   // 0..15
    const int m0 = blockIdx.x * 64;

    sh8 bh[8], bl[8];
#pragma unroll
    for (int q = 0; q < 8; ++q) {
        bh[q] = *(const sh8*)(WF + (wid*8 + q)*512 + lane*8);
        bl[q] = *(const sh8*)(WF + 65536 + (wid*8 + q)*512 + lane*8);
    }
    const int colg = wid*16 + (lane & 15);
    const float bwv = bias[colg];
    const float cxv = ctx[colg];

    if (PACKED) {
        const u32* src32 = (const u32*)A + (long)blockIdx.x * 16384;
        u32* dst = (u32*)a_pk;
        for (int idx = tid; idx < 16384; idx += 1024) {
            int mf = idx >> 11, q = (idx >> 8) & 7, l = (idx >> 2) & 63, c2 = idx & 3;
            int row16 = l & 15, hilo = row16 >> 3, rm = row16 & 7;
            int t = mf*8 + rm;
            int k = q*32 + (l >> 4)*8 + c2*2;
            dst[idx] = src32[(t*2 + hilo)*128 + (k >> 1)];
        }
    } else {
        for (int idx = tid; idx < 8192; idx += 1024) {
            int row = idx >> 7;            // 0..63
            int k   = (idx & 127) << 1;
            float2 v = *(const float2*)&A[(long)(m0 + row)*256 + k];
            u16 h0,l0,h1,l1; bf16_split(v.x,h0,l0); bf16_split(v.y,h1,l1);
            int mf = row >> 3, rm = row & 7;
            int q = k >> 5;
            int lh = (((k & 31) >> 3) << 4) | rm;
            int e = k & 7;
            *(u32*)&a_pk[mf][q][lh*8 + e]     = (u32)h0 | ((u32)h1 << 16);
            *(u32*)&a_pk[mf][q][(lh+8)*8 + e] = (u32)l0 | ((u32)l1 << 16);
        }
    }
    __syncthreads();

#pragma unroll
    for (int mf = 0; mf < 8; ++mf) {
        f32x4 acc = (f32x4){0.f,0.f,0.f,0.f};
#pragma unroll
        for (int q = 0; q < 8; ++q) {
            sh8 a = *(const sh8*)&a_pk[mf][q][lane*8];
            acc = __builtin_amdgcn_mfma_f32_16x16x32_bf16(a, bh[q], acc, 0,0,0);
            acc = __builtin_amdgcn_mfma_f32_16x16x32_bf16(a, bl[q], acc, 0,0,0);
        }
        float g[4];
#pragma unroll
        for (int r = 0; r < 4; ++r) g[r] = acc[r] + __shfl_xor(acc[r], 32);
        if ((lane >= 32) == (mf & 1)) {    // half-dedup: each half handles 4 mf
            float p[4];
#pragma unroll
            for (int r = 0; r < 4; ++r) p[r] = tanhf_(g[r] + bwv) * cxv;
#pragma unroll
            for (int r = 0; r < 4; ++r) {
                p[r] += __shfl_xor(p[r], 1);
                p[r] += __shfl_xor(p[r], 2);
                p[r] += __shfl_xor(p[r], 4);
                p[r] += __shfl_xor(p[r], 8);
            }
            if ((lane & 15) == 0) {
#pragma unroll
                for (int r = 0; r < 4; ++r)
                    pscore[mf][((lane >> 4) & 1)*4 + r][wid] = p[r];
            }
        }
    }
    __syncthreads();

    // softmax over T (per sentence group) in wave 0
    if (tid < 64) {
        float sc = 0.f;
#pragma unroll
        for (int w = 0; w < 16; ++w) sc += pscore[tid >> 3][tid & 7][w];
        float mx = sc;
#pragma unroll
        for (int m = 1; m < T; m <<= 1) mx = fmaxf(mx, __shfl_xor(mx, m));
        float e = __expf(sc - mx);
        float den = e;
#pragma unroll
        for (int m = 1; m < T; m <<= 1) den += __shfl_xor(den, m);
        aw[tid] = __fdividef(e, den);
    }
    __syncthreads();

    // weighted sum: h reconstructed from a_pk (hi+lo); thread -> (d-pair, t-group)
    if (tid < 512) {
        const int dp = (tid & 127) << 1;
        const int tg = tid >> 7;          // 0..3
        const int q = dp >> 5, lhb = ((dp & 31) >> 3) << 4, e = dp & 7;
        float acc0 = 0.f, acc1 = 0.f;
#pragma unroll
        for (int i = 0; i < 16; ++i) {
            int t = tg*16 + i;
            int mf = t >> 3, rm = t & 7;
            const u16* base = &a_pk[mf][q][(lhb | rm)*8 + e];
            u32 hh = *(const u32*)base;
            u32 ll = *(const u32*)(base + 64);
            float h0 = bf16_f((u16)hh) + bf16_f((u16)ll);
            float h1 = bf16_f((u16)(hh >> 16)) + bf16_f((u16)(ll >> 16));
            float w = aw[t];
            acc0 = fmaf(w, h0, acc0);
            acc1 = fmaf(w, h1, acc1);
        }
        red[tg][dp] = acc0; red[tg][dp + 1] = acc1;
    }
    __syncthreads();
    if (T == 64) {
        if (tid < 256)
            outp[(long)blockIdx.x*256 + tid] = red[0][tid] + red[1][tid] + red[2][tid] + red[3][tid];
    } else {
        if (tid < 512) {
            int sent = tid >> 8, dd = tid & 255;
            outp[((long)blockIdx.x*2 + sent)*256 + dd] = red[sent*2][dd] + red[sent*2 + 1][dd];
        }
    }
}

// ---------------- tiled GEMM (+bias) for sentence xp ----------------
__global__ __launch_bounds__(256)
void gemm_xp(const float* __restrict__ A,
             const float* __restrict__ WT, const float* __restrict__ bias,
             float* __restrict__ out, int N, int K)
{
    __shared__ float As[64*128];
    __shared__ float Bs[128*64];
    const int tid = threadIdx.x;
    const int m0 = blockIdx.x * 64;
    const int n0 = blockIdx.y * 64;
    const int tx = tid & 15, ty = tid >> 4;
    float acc[4][4];
#pragma unroll
    for (int i=0;i<4;i++)
#pragma unroll
        for (int c=0;c<4;c++) acc[i][c]=0.f;

    for (int kc = 0; kc < K; kc += 128) {
        if (kc) __syncthreads();
#pragma unroll
        for (int it = 0; it < 8; ++it) {
            int idx = tid + it*256;
            int r = idx >> 5, c4 = idx & 31;
            float4 v = *(const float4*)&A[(long)(m0 + r)*K + kc + (c4<<2)];
            *(float4*)&As[r*128 + ((c4 ^ (r & 7)) << 2)] = v;
        }
#pragma unroll
        for (int it = 0; it < 8; ++it) {
            int idx = tid + it*256;
            int k = idx >> 4, c4 = idx & 15;
            float4 v = *(const float4*)&WT[(long)(kc + k)*N + n0 + (c4<<2)];
            *(float4*)&Bs[k*64 + ((c4 ^ (k & 7)) << 2)] = v;
        }
        __syncthreads();
        const int swzA = (ty & 7) << 2;
#pragma unroll 4
        for (int k = 0; k < 128; ++k) {
            float4 b = *(const float4*)&Bs[k*64 + ((tx ^ (k & 7)) << 2)];
            int kx = k ^ swzA;
#pragma unroll
            for (int i=0;i<4;i++) {
                float a = As[(ty + 16*i)*128 + kx];
                acc[i][0] = fmaf(a, b.x, acc[i][0]);
                acc[i][1] = fmaf(a, b.y, acc[i][1]);
                acc[i][2] = fmaf(a, b.z, acc[i][2]);
                acc[i][3] = fmaf(a, b.w, acc[i][3]);
            }
        }
    }
    float4 bia = *(const float4*)&bias[n0 + (tx<<2)];
#pragma unroll
    for (int i=0;i<4;i++) {
        float4 res = make_float4(acc[i][0]+bia.x, acc[i][1]+bia.y, acc[i][2]+bia.z, acc[i][3]+bia.w);
        *(float4*)&out[(long)(m0 + ty + 16*i)*N + n0 + (tx<<2)] = res;
    }
}

// ---------------- sentence GRU (streamed weights; small) ----------------
template<int NSEQ, int T>
__global__ __launch_bounds__(512)
void gru_fused(const float* __restrict__ xp, const float4* __restrict__ whh4,
               const float* __restrict__ bhh, float* __restrict__ hout,
               int blocks_per_dir)
{
    const int bx = blockIdx.x;
    const int dir = bx / blocks_per_dir;
    const int blk = bx % blocks_per_dir;
    const int seq0 = blk * NSEQ;
    const int tid = threadIdx.x;
    const int kq = tid & 3;
    const int j  = tid >> 2;
    const float4* W = whh4 + (long)dir * 12288;
    __shared__ float h_lds[NSEQ][128];
    for (int idx = tid; idx < NSEQ*128; idx += 512) ((float*)h_lds)[idx] = 0.f;
    const float bhr = bhh[dir*384 + j];
    const float bhz = bhh[dir*384 + 128 + j];
    const float bhn = bhh[dir*384 + 256 + j];
    __syncthreads();

    for (int ts = 0; ts < T; ++ts) {
        const int t = dir ? (T - 1 - ts) : ts;
        float a0[NSEQ], a1[NSEQ], a2[NSEQ];
#pragma unroll
        for (int s=0;s<NSEQ;s++){a0[s]=0.f;a1[s]=0.f;a2[s]=0.f;}
#pragma unroll
        for (int ii = 0; ii < 8; ++ii) {
            const int k4 = kq + (ii << 2);
            float4 w0 = W[k4*384 + j];
            float4 w1 = W[k4*384 + 128 + j];
            float4 w2 = W[k4*384 + 256 + j];
#pragma unroll
            for (int s=0;s<NSEQ;s++) {
                float4 h4 = *(const float4*)&h_lds[s][k4 << 2];
                a0[s] = fmaf(w0.x,h4.x, fmaf(w0.y,h4.y, fmaf(w0.z,h4.z, fmaf(w0.w,h4.w, a0[s]))));
                a1[s] = fmaf(w1.x,h4.x, fmaf(w1.y,h4.y, fmaf(w1.z,h4.z, fmaf(w1.w,h4.w, a1[s]))));
                a2[s] = fmaf(w2.x,h4.x, fmaf(w2.y,h4.y, fmaf(w2.z,h4.z, fmaf(w2.w,h4.w, a2[s]))));
            }
        }
#pragma unroll
        for (int s=0;s<NSEQ;s++) {
            a0[s] += __shfl_xor(a0[s], 1); a0[s] += __shfl_xor(a0[s], 2);
            a1[s] += __shfl_xor(a1[s], 1); a1[s] += __shfl_xor(a1[s], 2);
            a2[s] += __shfl_xor(a2[s], 1); a2[s] += __shfl_xor(a2[s], 2);
        }
        __syncthreads();
        if (kq == 0) {
#pragma unroll
            for (int s=0;s<NSEQ;s++) {
                const float* xr = &xp[((long)(seq0+s)*T + t)*768 + dir*384];
                float r = sigmoidf_(xr[j]       + a0[s] + bhr);
                float z = sigmoidf_(xr[128 + j] + a1[s] + bhz);
                float nv = tanhf_(xr[256 + j] + r * (a2[s] + bhn));
                float hold = h_lds[s][j];
                float hnew = (1.f - z) * nv + z * hold;
                h_lds[s][j] = hnew;
                hout[((long)(seq0+s)*T + t)*256 + dir*128 + j] = hnew;
            }
        }
        __syncthreads();
    }
}

// ---------------- classifier ----------------
__global__ void classifier(const float* __restrict__ doc, const float* __restrict__ Wc,
                           const float* __restrict__ bc, float* __restrict__ out)
{
    int tid = threadIdx.x;
    if (tid < 320) {
        int b = tid / 10, c = tid % 10;
        float s = bc[c];
        for (int d = 0; d < 256; ++d) s = fmaf(doc[b*256 + d], Wc[c*256 + d], s);
        out[tid] = s;
    }
}

extern "C" void kernel_launch(void* const* d_in, const int* in_sizes, int n_in,
                              void* d_out, int out_size, void* d_ws, size_t ws_size,
                              hipStream_t stream) {
    const int*   X       = (const int*)  d_in[0];
    const float* emb     = (const float*)d_in[1];
    const float* w_ih_f  = (const float*)d_in[2];
    const float* w_hh_f  = (const float*)d_in[3];
    const float* b_ih_f  = (const float*)d_in[4];
    const float* b_hh_f  = (const float*)d_in[5];
    const float* w_ih_b  = (const float*)d_in[6];
    const float* w_hh_b  = (const float*)d_in[7];
    const float* b_ih_b  = (const float*)d_in[8];
    const float* b_hh_b  = (const float*)d_in[9];
    const float* Ww      = (const float*)d_in[10];
    const float* bw      = (const float*)d_in[11];
    const float* ctx_w   = (const float*)d_in[12];
    const float* s_ih_f  = (const float*)d_in[13];
    const float* s_hh_f  = (const float*)d_in[14];
    const float* sb_ih_f = (const float*)d_in[15];
    const float* sb_hh_f = (const float*)d_in[16];
    const float* s_ih_b  = (const float*)d_in[17];
    const float* s_hh_b  = (const float*)d_in[18];
    const float* sb_ih_b = (const float*)d_in[19];
    const float* sb_hh_b = (const float*)d_in[20];
    const float* Ws      = (const float*)d_in[21];
    const float* bs      = (const float*)d_in[22];
    const float* ctx_s   = (const float*)d_in[23];
    const float* Wc      = (const float*)d_in[24];
    const float* bc      = (const float*)d_in[25];
    float* ws  = (float*)d_ws;
    float* out = (float*)d_out;

    if (ws_size < (size_t)WS_FLOATS * 4) return;   // fail cleanly if scratch too small

    // 1. weight prep
    prep<<<2444, 256, 0, stream>>>(s_ih_f, s_ih_b, w_ih_f, w_ih_b,
                                   w_hh_f, w_hh_b, s_hh_f, s_hh_b,
                                   b_ih_f, b_ih_b, sb_ih_f, sb_ih_b,
                                   b_hh_f, b_hh_b, sb_hh_f, sb_hh_b, ws);
    prep2<<<768, 256, 0, stream>>>(w_hh_f, w_hh_b, (u16*)(ws + OFF_WFHH));
    prep3<<<1792, 256, 0, stream>>>(Ww, Ws, w_ih_f, w_ih_b,
                                    (u16*)(ws + OFF_WFW_W), (u16*)(ws + OFF_WFW_S),
                                    (u16*)(ws + OFF_WFX));

    // 2. fused word pipeline (round-17: waves_per_eu(3,3) register-budget pin)
    gru_word_full<<<256, 768, 0, stream>>>(
        X, emb, (const u16*)(ws + OFF_WFX), (const u16*)(ws + OFF_WFHH),
        b_ih_f, b_ih_b, b_hh_f, b_hh_b, (u16*)(ws + OFF_HW));

    // 3. fused word attention (decode-permute staging) -> sents
    attn_fused<64, true><<<1024, 1024, 0, stream>>>(
        ws + OFF_HW, (const u16*)(ws + OFF_WFW_W), bw, ctx_w, ws + OFF_SENTS);

    // 4. sentence xp
    gemm_xp<<<dim3(16, 12), 256, 0, stream>>>(
        ws + OFF_SENTS, ws + OFF_WIHT_S, ws + OFF_BIH_S, ws + OFF_XP_S, 768, 256);
    // 5. sentence GRU
    gru_fused<1, 32><<<64, 512, 0, stream>>>(
        ws + OFF_XP_S, (const float4*)(ws + OFF_W6) + 4*12288, ws + OFF_BHH_S, ws + OFF_HS, 32);
    // 6. fused sentence attention -> doc
    attn_fused<32, false><<<16, 1024, 0, stream>>>(
        ws + OFF_HS, (const u16*)(ws + OFF_WFW_S), bs, ctx_s, ws + OFF_DOC);
    // 7. classifier
    classifier<<<1, 320, 0, stream>>>(ws + OFF_DOC, Wc, bc, out);
}

// Round 4
// 350.520 us; speedup vs baseline: 1.8462x; 1.8462x over previous
//
#include <hip/hip_runtime.h>
#include <hip/hip_bf16.h>
#include <math.h>

// Problem constants
#define Bd 32
#define Sd 32
#define Ld 64
#define Ed 128
#define Hd 128
#define MW 65536   // B*S*L tokens
#define MS 1024    // B*S sentences

// ws layout (float offsets)
#define OFF_WIHT_S   0          // [k=256][g=768] sentence input-proj weights (fp32)
#define OFF_WFW_W    196608     // 131072 u16: word attn Ww B-frags hi/lo
#define OFF_WFW_S    262144     // 131072 u16: sent attn Ws B-frags hi/lo
#define OFF_W6       327680     // 6 sets x float4[k4=32][g=384] (sets 4,5 used: sentence GRU)
#define OFF_BIH_W    622592     // (unused, kept)
#define OFF_BIH_S    623360
#define OFF_BHH_W    624128     // (unused, kept)
#define OFF_BHH_S    624896
#define OFF_WFX      625664     // 196608 u16: word xp w_ih B-frags [dir][half][nt24][q4][l][e]
#define OFF_HW       723968     // 1024 sents x [t64][hilo2][k256] u16 = 33.5M u16
#define OFF_SENTS    17763328   // 1024 x 256
#define OFF_XP_S     18025472   // 1024 x 768
#define OFF_HS       18811904   // 1024 x 256
#define OFF_DOC      19078144   // 32 x 256
#define OFF_WFHH     19086336   // 196608 u16: W_hh MFMA B-frags hi/lo
#define WS_FLOATS    19184640   // 76.7 MB

typedef __attribute__((ext_vector_type(8))) short sh8;
typedef __attribute__((ext_vector_type(4))) float f32x4;
typedef unsigned short u16;
typedef unsigned int u32;

#define GLD  388   // G stride, 16 rows (hi s=0-7 rows 0-7, lo rows 8-15)
#define XPLD 385   // xp_lds stride (mod 32 = 1 -> banks spread)
#define HPLD 520   // h_pk per-q stride in u16 (q-pad spreads banks)

// Raw workgroup barrier: waits LDS/shfl (lgkmcnt) only, deliberately NOT vmcnt.
// __syncthreads() compiles to s_waitcnt vmcnt(0) lgkmcnt(0) + s_barrier; the vmcnt(0)
// drains the per-step hout global stores, which are never read back inside this
// kernel. Skipping that drain removes a ~300-500cy stall from each of the 128
// per-step barriers. LDS ordering (G, h_pk, xp_lds, a_pk, shfl) is fully covered.
__device__ __forceinline__ void barrier_lds_only() {
    asm volatile("s_waitcnt lgkmcnt(0)\n\ts_barrier" ::: "memory");
}

__device__ __forceinline__ float sigmoidf_(float x) {
    return __fdividef(1.0f, 1.0f + __expf(-x));
}
__device__ __forceinline__ float tanhf_(float x) {
    float t = __expf(-2.0f * fabsf(x));
    float r = __fdividef(1.0f - t, 1.0f + t);
    return copysignf(r, x);
}
__device__ __forceinline__ u16 bf16_hi(float f) {
    u32 x = __float_as_uint(f);
    return (u16)((x + 0x7fffu + ((x >> 16) & 1u)) >> 16);
}
__device__ __forceinline__ float bf16_f(u16 u) { return __uint_as_float(((u32)u) << 16); }
__device__ __forceinline__ void bf16_split(float f, u16& hi, u16& lo) {
    hi = bf16_hi(f);
    lo = bf16_hi(f - bf16_f(hi));
}

// ---------------- weight prep ----------------
__global__ void prep(const float* __restrict__ s_ih_f, const float* __restrict__ s_ih_b,
                     const float* __restrict__ w_ih_f, const float* __restrict__ w_ih_b,
                     const float* __restrict__ w_hh_f, const float* __restrict__ w_hh_b,
                     const float* __restrict__ s_hh_f, const float* __restrict__ s_hh_b,
                     const float* __restrict__ b_ih_f, const float* __restrict__ b_ih_b,
                     const float* __restrict__ sb_ih_f, const float* __restrict__ sb_ih_b,
                     const float* __restrict__ b_hh_f, const float* __restrict__ b_hh_b,
                     const float* __restrict__ sb_hh_f, const float* __restrict__ sb_hh_b,
                     float* __restrict__ ws)
{
    int i = blockIdx.x * 256 + threadIdx.x;
    if (i < 196608) {  // WIHT_S [k=256][768]
        int k = i / 768, g = i % 768;
        ws[OFF_WIHT_S + i] = (g < 384) ? s_ih_f[g*256 + k] : s_ih_b[(g-384)*256 + k];
        return;
    }
    i -= 196608;
    if (i < 131072) return;   // frag buffers written by prep3
    i -= 131072;
    if (i < 294912) {  // W6 (sets 4,5 used by sentence GRU)
        int set = i / 49152, rem = i % 49152;
        int k4 = rem / 1536, r2 = rem % 1536, g = r2 >> 2, sub = r2 & 3;
        const float* w = (set==0) ? w_ih_f : (set==1) ? w_ih_b : (set==2) ? w_hh_f
                       : (set==3) ? w_hh_b : (set==4) ? s_hh_f : s_hh_b;
        ws[OFF_W6 + i] = w[g*128 + k4*4 + sub];
        return;
    }
    i -= 294912;
    if (i < 768) { ws[OFF_BIH_W + i] = (i<384) ? b_ih_f[i] : b_ih_b[i-384]; return; }
    i -= 768;
    if (i < 768) { ws[OFF_BIH_S + i] = (i<384) ? sb_ih_f[i] : sb_ih_b[i-384]; return; }
    i -= 768;
    if (i < 768) { ws[OFF_BHH_W + i] = (i<384) ? b_hh_f[i] : b_hh_b[i-384]; return; }
    i -= 768;
    if (i < 768) { ws[OFF_BHH_S + i] = (i<384) ? sb_hh_f[i] : sb_hh_b[i-384]; return; }
}

// ---------------- prep2: W_hh into MFMA B-frag order, bf16 hi/lo ----------------
// layout: [dir2][half2][nt24][q4][lane64][elem8] ushort
__global__ void prep2(const float* __restrict__ w_hh_f, const float* __restrict__ w_hh_b,
                      u16* __restrict__ WFo)
{
    int i = blockIdx.x * 256 + threadIdx.x;   // < 196608
    int within = i % 49152;
    int combo  = i / 49152;      // dir*2 + half
    int half = combo & 1, dir = combo >> 1;
    int nt  = within / 2048;
    int r2  = within % 2048;
    int q   = r2 >> 9;
    int r3  = r2 & 511;
    int l   = r3 >> 3, e = r3 & 7;
    int n = nt*16 + (l & 15);
    int k = q*32 + ((l >> 4) << 3) + e;
    const float* src = dir ? w_hh_b : w_hh_f;
    float v = src[n*128 + k];
    u16 hi = bf16_hi(v);
    WFo[i] = half ? bf16_hi(v - bf16_f(hi)) : hi;
}

// ---------------- prep3: attn (Ww,Ws) and xp (w_ih) weights into B-frag hi/lo ---------
// WFW_*: [half2][nt16][q8][l64][e8]; WFX: [dir2][half2][nt24][q4][l64][e8]
__global__ void prep3(const float* __restrict__ Ww, const float* __restrict__ Ws,
                      const float* __restrict__ w_ih_f, const float* __restrict__ w_ih_b,
                      u16* __restrict__ WFW_W, u16* __restrict__ WFW_S,
                      u16* __restrict__ WFX)
{
    int i = blockIdx.x * 256 + threadIdx.x;   // < 458752
    if (i < 262144) {
        int which = i / 131072;       // 0=Ww, 1=Ws
        int w = i % 131072;
        int half = w / 65536;
        int r = w % 65536;
        int nt = r / 4096;
        int r2 = r % 4096;
        int q = r2 / 512;
        int l = (r2 % 512) >> 3, e = r2 & 7;
        int n = nt*16 + (l & 15);
        int k = q*32 + ((l >> 4) << 3) + e;
        const float* src = which ? Ws : Ww;
        float v = src[n*256 + k];
        u16 hi = bf16_hi(v);
        u16 o = half ? bf16_hi(v - bf16_f(hi)) : hi;
        (which ? WFW_S : WFW_W)[w] = o;
        return;
    }
    i -= 262144;
    if (i < 196608) {
        int w = i % 98304;
        int dir = i / 98304;
        int half = w / 49152;
        int r = w % 49152;
        int nt = r / 2048;
        int r2 = r % 2048;
        int q = r2 / 512;
        int l = (r2 % 512) >> 3, e = r2 & 7;
        int n = nt*16 + (l & 15);
        int k = q*32 + ((l >> 4) << 3) + e;
        const float* src = dir ? w_ih_b : w_ih_f;
        float v = src[n*128 + k];
        u16 hi = bf16_hi(v);
        WFX[i] = half ? bf16_hi(v - bf16_f(hi)) : hi;
        return;
    }
}

// ---------------- fused word pipeline: gather + xp-GEMM (LDS) + recurrence ----------
// ROUND-18: exact ROUND-14 geometry (the 195us/349us verified config: grid 256,
// block 768, 8 seqs/block, 8 chunks x 8 steps, G round-trip via uni4 union, 80 VGPR,
// no spill). Rounds 15-17 post-mortem: the col-grouped in-register-gate design needs
// 96 VGPRs of W_hh frags; the allocator's ~84-reg budget is immovable (bare
// launch_bounds, (768,3), and amdgpu_waves_per_eu(3,3) all produced identical
// VGPR_Count=84 + 300MB scratch traffic). Reverted.
// Two register-neutral changes on top of round-14:
//  * barrier_lds_only() for all intra-chunk barriers: skips the vmcnt(0) store-drain
//    __syncthreads() would impose at each of the 128+ per-step barriers (hout stores
//    are never read back in-kernel; LDS ordering fully covered by lgkmcnt).
//  * paired u32 hout stores (even j: hi-pair word, odd j: lo-pair word — the same
//    words already built for h_pk), halving global store count (proven in r16/r17).
__global__ __launch_bounds__(768)
void gru_word_full(const int* __restrict__ X, const float* __restrict__ emb,
                   const u16* __restrict__ WFX, const u16* __restrict__ WFHH,
                   const float* __restrict__ b_ih_f, const float* __restrict__ b_ih_b,
                   const float* __restrict__ b_hh_f, const float* __restrict__ b_hh_b,
                   u16* __restrict__ houtp)
{
    const int bx = blockIdx.x;
    const int dir = bx >> 7;
    const int blk = bx & 127;
    const int seq0 = blk * 8;
    const int tid = threadIdx.x;
    const int lane = tid & 63;
    const int wid = tid >> 6;            // 0..11

    __shared__ float xp_lds[64 * XPLD];      // 98560 B (rows = s*8 + tt)
    __shared__ f32x4 uni4[2048];             // 32768 B union: a_pk (32 KB) / G (24.8 KB)
    __shared__ u16 h_pk[4 * HPLD];           // 4160 B (hi rows 0-7, lo rows 8-15)
    __shared__ int ids_s[8][64];             // 2048 B
    float* G = (float*)uni4;                 // [16][GLD]
    u16* a_pk = (u16*)uni4;                  // [8 mf][4 q][512] u16

    const int j = tid & 127;
    const int sg = tid >> 7;             // 0..3 gate threads (s = sg, sg+4)
    const bool gthread = tid < 512;
    const float* bih = dir ? b_ih_b : b_ih_f;
    const float* bhh = dir ? b_hh_b : b_hh_f;
    float bhr = 0.f, bhz = 0.f, bhn = 0.f;
    if (gthread) { bhr = bhh[j]; bhz = bhh[128 + j]; bhn = bhh[256 + j]; }

    const u16* WXbase = WFX + (long)dir * 98304;
    const u16* WHbase = WFHH + (long)dir * 98304;
    const int nt0 = wid*2, nt1 = wid*2 + 1;
    const int c0 = nt0*16 + (lane & 15);
    const int c1 = nt1*16 + (lane & 15);
    // gate-thread h_pk write decomposition for k = j
    const int qj = j >> 5, subkj = (j >> 3) & 3, ej = j & 7;

    for (int i = tid; i < 512; i += 768)
        ids_s[i >> 6][i & 63] = X[(long)(seq0 + (i >> 6))*64 + (i & 63)];
    for (int i = tid; i < 4*HPLD; i += 768) h_pk[i] = 0;
    __syncthreads();

    float hprev0 = 0.f, hprev1 = 0.f;
    for (int c = 0; c < 8; ++c) {
        asm volatile("" ::: "memory");   // no cross-chunk hoisting of weight loads
        // ---- load W_ih frags (this chunk only) ----
        sh8 xh0[4], xl0[4], xh1[4], xl1[4];
#pragma unroll
        for (int q = 0; q < 4; ++q) {
            xh0[q] = *(const sh8*)(WXbase + (nt0*4 + q)*512 + lane*8);
            xl0[q] = *(const sh8*)(WXbase + 49152 + (nt0*4 + q)*512 + lane*8);
            xh1[q] = *(const sh8*)(WXbase + (nt1*4 + q)*512 + lane*8);
            xl1[q] = *(const sh8*)(WXbase + 49152 + (nt1*4 + q)*512 + lane*8);
        }
        const float bv0 = bih[c0], bv1 = bih[c1];
        // ---- stage gathered embeddings: 4096 u32-pairs, bank-spread index map ----
        // idx bits: [1:0]=cc [4:2]=rm(tt) [6:5]=subk [8:7]=q [11:9]=mfs(s)
        for (int idx = tid; idx < 4096; idx += 768) {
            int cc = idx & 3, rm = (idx >> 2) & 7, subk = (idx >> 5) & 3;
            int q = (idx >> 7) & 3, mfs = idx >> 9;
            int ts = c*8 + rm;
            int t = dir ? 63 - ts : ts;
            int kk = q*32 + subk*8 + cc*2;
            int id = ids_s[mfs][t];
            float2 v = make_float2(0.f, 0.f);
            if (id != 0) v = *(const float2*)&emb[(long)id*128 + kk];
            u16 h0,l0,h1,l1; bf16_split(v.x,h0,l0); bf16_split(v.y,h1,l1);
            int lh = subk*16 + rm;
            *(u32*)&a_pk[(mfs*4 + q)*512 + lh*8 + cc*2]       = (u32)h0 | ((u32)h1 << 16);
            *(u32*)&a_pk[(mfs*4 + q)*512 + (lh+8)*8 + cc*2]   = (u32)l0 | ((u32)l1 << 16);
        }
        barrier_lds_only();
        // ---- xp MFMA: 8 m-frags -> xp_lds (+bias), half-dedup epilogue ----
#pragma unroll
        for (int mf = 0; mf < 8; ++mf) {
            f32x4 A0 = (f32x4){0.f,0.f,0.f,0.f};
            f32x4 A1 = (f32x4){0.f,0.f,0.f,0.f};
#pragma unroll
            for (int q = 0; q < 4; ++q) {
                sh8 a = *(const sh8*)&a_pk[(mf*4 + q)*512 + lane*8];
                A0 = __builtin_amdgcn_mfma_f32_16x16x32_bf16(a, xh0[q], A0, 0,0,0);
                A0 = __builtin_amdgcn_mfma_f32_16x16x32_bf16(a, xl0[q], A0, 0,0,0);
                A1 = __builtin_amdgcn_mfma_f32_16x16x32_bf16(a, xh1[q], A1, 0,0,0);
                A1 = __builtin_amdgcn_mfma_f32_16x16x32_bf16(a, xl1[q], A1, 0,0,0);
            }
            float g0[4], g1[4];
#pragma unroll
            for (int r = 0; r < 4; ++r) {
                g0[r] = A0[r] + __shfl_xor(A0[r], 32);
                g1[r] = A1[r] + __shfl_xor(A1[r], 32);
            }
            if ((lane >= 32) == (mf & 1)) {
                int row = mf*8 + ((lane >> 4) & 1)*4;
#pragma unroll
                for (int r = 0; r < 4; ++r) {
                    xp_lds[(row+r)*XPLD + c0] = g0[r] + bv0;
                    xp_lds[(row+r)*XPLD + c1] = g1[r] + bv1;
                }
            }
        }
        barrier_lds_only();   // xp ready; a_pk region free -> G
        asm volatile("" ::: "memory");
        // ---- load W_hh frags ----
        sh8 wh0[4], wl0[4], wh1[4], wl1[4];
#pragma unroll
        for (int q = 0; q < 4; ++q) {
            wh0[q] = *(const sh8*)(WHbase + (nt0*4 + q)*512 + lane*8);
            wl0[q] = *(const sh8*)(WHbase + 49152 + (nt0*4 + q)*512 + lane*8);
            wh1[q] = *(const sh8*)(WHbase + (nt1*4 + q)*512 + lane*8);
            wl1[q] = *(const sh8*)(WHbase + 49152 + (nt1*4 + q)*512 + lane*8);
        }
        // ---- 8 recurrence steps ----
        for (int tt = 0; tt < 8; ++tt) {
            const int ts = c*8 + tt;
            const int t = dir ? 63 - ts : ts;
            f32x4 acc0 = (f32x4){0.f,0.f,0.f,0.f};
            f32x4 acc1 = (f32x4){0.f,0.f,0.f,0.f};
#pragma unroll
            for (int q = 0; q < 4; ++q) {
                sh8 hp = *(const sh8*)&h_pk[q*HPLD + lane*8];
                acc0 = __builtin_amdgcn_mfma_f32_16x16x32_bf16(hp, wh0[q], acc0, 0,0,0);
                acc0 = __builtin_amdgcn_mfma_f32_16x16x32_bf16(hp, wl0[q], acc0, 0,0,0);
                acc1 = __builtin_amdgcn_mfma_f32_16x16x32_bf16(hp, wh1[q], acc1, 0,0,0);
                acc1 = __builtin_amdgcn_mfma_f32_16x16x32_bf16(hp, wl1[q], acc1, 0,0,0);
            }
            {
                const int col16 = lane & 15;
                const int row0  = (lane >> 4) << 2;
#pragma unroll
                for (int r = 0; r < 4; ++r) {
                    G[(row0+r)*GLD + nt0*16 + col16] = acc0[r];
                    G[(row0+r)*GLD + nt1*16 + col16] = acc1[r];
                }
            }
            barrier_lds_only();
            if (gthread) {
#pragma unroll
                for (int si = 0; si < 2; ++si) {
                    const int s = sg + si*4;
                    float gr  = G[s*GLD + j]       + G[(s+8)*GLD + j]       + bhr;
                    float gz  = G[s*GLD + 128 + j] + G[(s+8)*GLD + 128 + j] + bhz;
                    float gnh = G[s*GLD + 256 + j] + G[(s+8)*GLD + 256 + j] + bhn;
                    const float* xrow = &xp_lds[(s*8 + tt)*XPLD];
                    float r  = sigmoidf_(xrow[j] + gr);
                    float z  = sigmoidf_(xrow[128 + j] + gz);
                    float nv = tanhf_(xrow[256 + j] + r * gnh);
                    float hold = si ? hprev1 : hprev0;
                    float hnew = (1.f - z) * nv + z * hold;
                    if (si) hprev1 = hnew; else hprev0 = hnew;
                    u16 hh, hl; bf16_split(hnew, hh, hl);
                    // paired u32 writes: even j handles the hi row pair, odd j the lo
                    u16 ohh = (u16)__shfl_xor((int)hh, 1);
                    u16 ohl = (u16)__shfl_xor((int)hl, 1);
                    const long tbase = ((long)(seq0 + s)*64 + t)*512 + dir*128;
                    if ((j & 1) == 0) {
                        u32 w = (u32)hh | ((u32)ohh << 16);
                        *(u32*)&h_pk[qj*HPLD + (subkj*16 + s)*8 + ej] = w;
                        *(u32*)&houtp[tbase + j] = w;
                    } else {
                        u32 w = (u32)ohl | ((u32)hl << 16);
                        *(u32*)&h_pk[qj*HPLD + (subkj*16 + s + 8)*8 + (ej - 1)] = w;
                        *(u32*)&houtp[tbase + 256 + (j - 1)] = w;
                    }
                }
            }
            barrier_lds_only();
        }
    }
}

// ---------------- fused attention: score MFMA + tanh/ctx + softmax + pool ----------
// PACKED=true: A = hout u16 [sent][t][hilo][k256]; staged via decode-permute copy.
// PACKED=false: A is fp32 [M][256], staged with bf16 split (sentence level).
template<int T, bool PACKED>
__global__ __launch_bounds__(1024)
void attn_fused(const float* __restrict__ A, const u16* __restrict__ WF,
                const float* __restrict__ bias, const float* __restrict__ ctx,
                float* __restrict__ outp)
{
    __shared__ u16 a_pk[8][8][512];    // 64 KB
    __shared__ float pscore[8][8][17];
    __shared__ float aw[64];
    __shared__ float red[4][256];
    const int tid = threadIdx.x;
    const int lane = tid & 63;
    const int wid = tid >> 6;   // 0..15
    const int m0 = blockIdx.x * 64;

    sh8 bh[8], bl[8];
#pragma unroll
    for (int q = 0; q < 8; ++q) {
        bh[q] = *(const sh8*)(WF + (wid*8 + q)*512 + lane*8);
        bl[q] = *(const sh8*)(WF + 65536 + (wid*8 + q)*512 + lane*8);
    }
    const int colg = wid*16 + (lane & 15);
    const float bwv = bias[colg];
    const float cxv = ctx[colg];

    if (PACKED) {
        const u32* src32 = (const u32*)A + (long)blockIdx.x * 16384;
        u32* dst = (u32*)a_pk;
        for (int idx = tid; idx < 16384; idx += 1024) {
            int mf = idx >> 11, q = (idx >> 8) & 7, l = (idx >> 2) & 63, c2 = idx & 3;
            int row16 = l & 15, hilo = row16 >> 3, rm = row16 & 7;
            int t = mf*8 + rm;
            int k = q*32 + (l >> 4)*8 + c2*2;
            dst[idx] = src32[(t*2 + hilo)*128 + (k >> 1)];
        }
    } else {
        for (int idx = tid; idx < 8192; idx += 1024) {
            int row = idx >> 7;            // 0..63
            int k   = (idx & 127) << 1;
            float2 v = *(const float2*)&A[(long)(m0 + row)*256 + k];
            u16 h0,l0,h1,l1; bf16_split(v.x,h0,l0); bf16_split(v.y,h1,l1);
            int mf = row >> 3, rm = row & 7;
            int q = k >> 5;
            int lh = (((k & 31) >> 3) << 4) | rm;
            int e = k & 7;
            *(u32*)&a_pk[mf][q][lh*8 + e]     = (u32)h0 | ((u32)h1 << 16);
            *(u32*)&a_pk[mf][q][(lh+8)*8 + e] = (u32)l0 | ((u32)l1 << 16);
        }
    }
    __syncthreads();

#pragma unroll
    for (int mf = 0; mf < 8; ++mf) {
        f32x4 acc = (f32x4){0.f,0.f,0.f,0.f};
#pragma unroll
        for (int q = 0; q < 8; ++q) {
            sh8 a = *(const sh8*)&a_pk[mf][q][lane*8];
            acc = __builtin_amdgcn_mfma_f32_16x16x32_bf16(a, bh[q], acc, 0,0,0);
            acc = __builtin_amdgcn_mfma_f32_16x16x32_bf16(a, bl[q], acc, 0,0,0);
        }
        float g[4];
#pragma unroll
        for (int r = 0; r < 4; ++r) g[r] = acc[r] + __shfl_xor(acc[r], 32);
        if ((lane >= 32) == (mf & 1)) {    // half-dedup: each half handles 4 mf
            float p[4];
#pragma unroll
            for (int r = 0; r < 4; ++r) p[r] = tanhf_(g[r] + bwv) * cxv;
#pragma unroll
            for (int r = 0; r < 4; ++r) {
                p[r] += __shfl_xor(p[r], 1);
                p[r] += __shfl_xor(p[r], 2);
                p[r] += __shfl_xor(p[r], 4);
                p[r] += __shfl_xor(p[r], 8);
            }
            if ((lane & 15) == 0) {
#pragma unroll
                for (int r = 0; r < 4; ++r)
                    pscore[mf][((lane >> 4) & 1)*4 + r][wid] = p[r];
            }
        }
    }
    __syncthreads();

    // softmax over T (per sentence group) in wave 0
    if (tid < 64) {
        float sc = 0.f;
#pragma unroll
        for (int w = 0; w < 16; ++w) sc += pscore[tid >> 3][tid & 7][w];
        float mx = sc;
#pragma unroll
        for (int m = 1; m < T; m <<= 1) mx = fmaxf(mx, __shfl_xor(mx, m));
        float e = __expf(sc - mx);
        float den = e;
#pragma unroll
        for (int m = 1; m < T; m <<= 1) den += __shfl_xor(den, m);
        aw[tid] = __fdividef(e, den);
    }
    __syncthreads();

    // weighted sum: h reconstructed from a_pk (hi+lo); thread -> (d-pair, t-group)
    if (tid < 512) {
        const int dp = (tid & 127) << 1;
        const int tg = tid >> 7;          // 0..3
        const int q = dp >> 5, lhb = ((dp & 31) >> 3) << 4, e = dp & 7;
        float acc0 = 0.f, acc1 = 0.f;
#pragma unroll
        for (int i = 0; i < 16; ++i) {
            int t = tg*16 + i;
            int mf = t >> 3, rm = t & 7;
            const u16* base = &a_pk[mf][q][(lhb | rm)*8 + e];
            u32 hh = *(const u32*)base;
            u32 ll = *(const u32*)(base + 64);
            float h0 = bf16_f((u16)hh) + bf16_f((u16)ll);
            float h1 = bf16_f((u16)(hh >> 16)) + bf16_f((u16)(ll >> 16));
            float w = aw[t];
            acc0 = fmaf(w, h0, acc0);
            acc1 = fmaf(w, h1, acc1);
        }
        red[tg][dp] = acc0; red[tg][dp + 1] = acc1;
    }
    __syncthreads();
    if (T == 64) {
        if (tid < 256)
            outp[(long)blockIdx.x*256 + tid] = red[0][tid] + red[1][tid] + red[2][tid] + red[3][tid];
    } else {
        if (tid < 512) {
            int sent = tid >> 8, dd = tid & 255;
            outp[((long)blockIdx.x*2 + sent)*256 + dd] = red[sent*2][dd] + red[sent*2 + 1][dd];
        }
    }
}

// ---------------- tiled GEMM (+bias) for sentence xp ----------------
__global__ __launch_bounds__(256)
void gemm_xp(const float* __restrict__ A,
             const float* __restrict__ WT, const float* __restrict__ bias,
             float* __restrict__ out, int N, int K)
{
    __shared__ float As[64*128];
    __shared__ float Bs[128*64];
    const int tid = threadIdx.x;
    const int m0 = blockIdx.x * 64;
    const int n0 = blockIdx.y * 64;
    const int tx = tid & 15, ty = tid >> 4;
    float acc[4][4];
#pragma unroll
    for (int i=0;i<4;i++)
#pragma unroll
        for (int c=0;c<4;c++) acc[i][c]=0.f;

    for (int kc = 0; kc < K; kc += 128) {
        if (kc) __syncthreads();
#pragma unroll
        for (int it = 0; it < 8; ++it) {
            int idx = tid + it*256;
            int r = idx >> 5, c4 = idx & 31;
            float4 v = *(const float4*)&A[(long)(m0 + r)*K + kc + (c4<<2)];
            *(float4*)&As[r*128 + ((c4 ^ (r & 7)) << 2)] = v;
        }
#pragma unroll
        for (int it = 0; it < 8; ++it) {
            int idx = tid + it*256;
            int k = idx >> 4, c4 = idx & 15;
            float4 v = *(const float4*)&WT[(long)(kc + k)*N + n0 + (c4<<2)];
            *(float4*)&Bs[k*64 + ((c4 ^ (k & 7)) << 2)] = v;
        }
        __syncthreads();
        const int swzA = (ty & 7) << 2;
#pragma unroll 4
        for (int k = 0; k < 128; ++k) {
            float4 b = *(const float4*)&Bs[k*64 + ((tx ^ (k & 7)) << 2)];
            int kx = k ^ swzA;
#pragma unroll
            for (int i=0;i<4;i++) {
                float a = As[(ty + 16*i)*128 + kx];
                acc[i][0] = fmaf(a, b.x, acc[i][0]);
                acc[i][1] = fmaf(a, b.y, acc[i][1]);
                acc[i][2] = fmaf(a, b.z, acc[i][2]);
                acc[i][3] = fmaf(a, b.w, acc[i][3]);
            }
        }
    }
    float4 bia = *(const float4*)&bias[n0 + (tx<<2)];
#pragma unroll
    for (int i=0;i<4;i++) {
        float4 res = make_float4(acc[i][0]+bia.x, acc[i][1]+bia.y, acc[i][2]+bia.z, acc[i][3]+bia.w);
        *(float4*)&out[(long)(m0 + ty + 16*i)*N + n0 + (tx<<2)] = res;
    }
}

// ---------------- sentence GRU (streamed weights; small) ----------------
template<int NSEQ, int T>
__global__ __launch_bounds__(512)
void gru_fused(const float* __restrict__ xp, const float4* __restrict__ whh4,
               const float* __restrict__ bhh, float* __restrict__ hout,
               int blocks_per_dir)
{
    const int bx = blockIdx.x;
    const int dir = bx / blocks_per_dir;
    const int blk = bx % blocks_per_dir;
    const int seq0 = blk * NSEQ;
    const int tid = threadIdx.x;
    const int kq = tid & 3;
    const int j  = tid >> 2;
    const float4* W = whh4 + (long)dir * 12288;
    __shared__ float h_lds[NSEQ][128];
    for (int idx = tid; idx < NSEQ*128; idx += 512) ((float*)h_lds)[idx] = 0.f;
    const float bhr = bhh[dir*384 + j];
    const float bhz = bhh[dir*384 + 128 + j];
    const float bhn = bhh[dir*384 + 256 + j];
    __syncthreads();

    for (int ts = 0; ts < T; ++ts) {
        const int t = dir ? (T - 1 - ts) : ts;
        float a0[NSEQ], a1[NSEQ], a2[NSEQ];
#pragma unroll
        for (int s=0;s<NSEQ;s++){a0[s]=0.f;a1[s]=0.f;a2[s]=0.f;}
#pragma unroll
        for (int ii = 0; ii < 8; ++ii) {
            const int k4 = kq + (ii << 2);
            float4 w0 = W[k4*384 + j];
            float4 w1 = W[k4*384 + 128 + j];
            float4 w2 = W[k4*384 + 256 + j];
#pragma unroll
            for (int s=0;s<NSEQ;s++) {
                float4 h4 = *(const float4*)&h_lds[s][k4 << 2];
                a0[s] = fmaf(w0.x,h4.x, fmaf(w0.y,h4.y, fmaf(w0.z,h4.z, fmaf(w0.w,h4.w, a0[s]))));
                a1[s] = fmaf(w1.x,h4.x, fmaf(w1.y,h4.y, fmaf(w1.z,h4.z, fmaf(w1.w,h4.w, a1[s]))));
                a2[s] = fmaf(w2.x,h4.x, fmaf(w2.y,h4.y, fmaf(w2.z,h4.z, fmaf(w2.w,h4.w, a2[s]))));
            }
        }
#pragma unroll
        for (int s=0;s<NSEQ;s++) {
            a0[s] += __shfl_xor(a0[s], 1); a0[s] += __shfl_xor(a0[s], 2);
            a1[s] += __shfl_xor(a1[s], 1); a1[s] += __shfl_xor(a1[s], 2);
            a2[s] += __shfl_xor(a2[s], 1); a2[s] += __shfl_xor(a2[s], 2);
        }
        __syncthreads();
        if (kq == 0) {
#pragma unroll
            for (int s=0;s<NSEQ;s++) {
                const float* xr = &xp[((long)(seq0+s)*T + t)*768 + dir*384];
                float r = sigmoidf_(xr[j]       + a0[s] + bhr);
                float z = sigmoidf_(xr[128 + j] + a1[s] + bhz);
                float nv = tanhf_(xr[256 + j] + r * (a2[s] + bhn));
                float hold = h_lds[s][j];
                float hnew = (1.f - z) * nv + z * hold;
                h_lds[s][j] = hnew;
                hout[((long)(seq0+s)*T + t)*256 + dir*128 + j] = hnew;
            }
        }
        __syncthreads();
    }
}

// ---------------- classifier ----------------
__global__ void classifier(const float* __restrict__ doc, const float* __restrict__ Wc,
                           const float* __restrict__ bc, float* __restrict__ out)
{
    int tid = threadIdx.x;
    if (tid < 320) {
        int b = tid / 10, c = tid % 10;
        float s = bc[c];
        for (int d = 0; d < 256; ++d) s = fmaf(doc[b*256 + d], Wc[c*256 + d], s);
        out[tid] = s;
    }
}

extern "C" void kernel_launch(void* const* d_in, const int* in_sizes, int n_in,
                              void* d_out, int out_size, void* d_ws, size_t ws_size,
                              hipStream_t stream) {
    const int*   X       = (const int*)  d_in[0];
    const float* emb     = (const float*)d_in[1];
    const float* w_ih_f  = (const float*)d_in[2];
    const float* w_hh_f  = (const float*)d_in[3];
    const float* b_ih_f  = (const float*)d_in[4];
    const float* b_hh_f  = (const float*)d_in[5];
    const float* w_ih_b  = (const float*)d_in[6];
    const float* w_hh_b  = (const float*)d_in[7];
    const float* b_ih_b  = (const float*)d_in[8];
    const float* b_hh_b  = (const float*)d_in[9];
    const float* Ww      = (const float*)d_in[10];
    const float* bw      = (const float*)d_in[11];
    const float* ctx_w   = (const float*)d_in[12];
    const float* s_ih_f  = (const float*)d_in[13];
    const float* s_hh_f  = (const float*)d_in[14];
    const float* sb_ih_f = (const float*)d_in[15];
    const float* sb_hh_f = (const float*)d_in[16];
    const float* s_ih_b  = (const float*)d_in[17];
    const float* s_hh_b  = (const float*)d_in[18];
    const float* sb_ih_b = (const float*)d_in[19];
    const float* sb_hh_b = (const float*)d_in[20];
    const float* Ws      = (const float*)d_in[21];
    const float* bs      = (const float*)d_in[22];
    const float* ctx_s   = (const float*)d_in[23];
    const float* Wc      = (const float*)d_in[24];
    const float* bc      = (const float*)d_in[25];
    float* ws  = (float*)d_ws;
    float* out = (float*)d_out;

    if (ws_size < (size_t)WS_FLOATS * 4) return;   // fail cleanly if scratch too small

    // 1. weight prep
    prep<<<2444, 256, 0, stream>>>(s_ih_f, s_ih_b, w_ih_f, w_ih_b,
                                   w_hh_f, w_hh_b, s_hh_f, s_hh_b,
                                   b_ih_f, b_ih_b, sb_ih_f, sb_ih_b,
                                   b_hh_f, b_hh_b, sb_hh_f, sb_hh_b, ws);
    prep2<<<768, 256, 0, stream>>>(w_hh_f, w_hh_b, (u16*)(ws + OFF_WFHH));
    prep3<<<1792, 256, 0, stream>>>(Ww, Ws, w_ih_f, w_ih_b,
                                    (u16*)(ws + OFF_WFW_W), (u16*)(ws + OFF_WFW_S),
                                    (u16*)(ws + OFF_WFX));

    // 2. fused word pipeline (round-18: round-14 geometry + lds-only barriers +
    //    paired u32 hout stores)
    gru_word_full<<<256, 768, 0, stream>>>(
        X, emb, (const u16*)(ws + OFF_WFX), (const u16*)(ws + OFF_WFHH),
        b_ih_f, b_ih_b, b_hh_f, b_hh_b, (u16*)(ws + OFF_HW));

    // 3. fused word attention (decode-permute staging) -> sents
    attn_fused<64, true><<<1024, 1024, 0, stream>>>(
        ws + OFF_HW, (const u16*)(ws + OFF_WFW_W), bw, ctx_w, ws + OFF_SENTS);

    // 4. sentence xp
    gemm_xp<<<dim3(16, 12), 256, 0, stream>>>(
        ws + OFF_SENTS, ws + OFF_WIHT_S, ws + OFF_BIH_S, ws + OFF_XP_S, 768, 256);
    // 5. sentence GRU
    gru_fused<1, 32><<<64, 512, 0, stream>>>(
        ws + OFF_XP_S, (const float4*)(ws + OFF_W6) + 4*12288, ws + OFF_BHH_S, ws + OFF_HS, 32);
    // 6. fused sentence attention -> doc
    attn_fused<32, false><<<16, 1024, 0, stream>>>(
        ws + OFF_HS, (const u16*)(ws + OFF_WFW_S), bs, ctx_s, ws + OFF_DOC);
    // 7. classifier
    classifier<<<1, 320, 0, stream>>>(ws + OFF_DOC, Wc, bc, out);
}